// Round 15
// baseline (237.088 us; speedup 1.0000x reference)
//
#include <hip/hip_runtime.h>

// ---------------------------------------------------------------------------
// TransformerBlockQuantum: B=2,S=2048,E=1024,H=32,DK=32,FFN=4096
// GEMMs: bf16 MFMA 16x16x32, LDS dbuf single-barrier loop, XCD swizzle.
// FFN2 = BN=128 split-K 4-way, bf16 partials. Prep fused. bf16 residual.
// Attention (this round): 3-buffer LDS pipeline, counted vmcnt + raw
// s_barrier (loads stay 2 tiles in flight; no vmcnt(0) drain in loop).
// ws layout (MB):
//  [0,6) QKV BT  [6,8)WoT [8,16)W1T [16,24)W2T
//  [24,32) r1b (bf16)   [40,72) xb/qh/kh/vT then hf   [72,88) ao then p2/p3
//  FFN2 partials: p0[0,8) p1[8,16) p2[72,80) p3[80,88)
// ---------------------------------------------------------------------------

typedef unsigned short u16;
typedef unsigned int u32;
typedef __bf16 bf16x8 __attribute__((ext_vector_type(8)));
typedef float f32x4 __attribute__((ext_vector_type(4)));
typedef float f32x16 __attribute__((ext_vector_type(16)));

__device__ __forceinline__ u16 f2b(float f) {
  union { float f; unsigned u; } x; x.f = f;
  unsigned r = x.u + 0x7FFFu + ((x.u >> 16) & 1u);
  return (u16)(r >> 16);
}

__device__ __forceinline__ float b2f(u16 u) {
  union { u32 u; float f; } x; x.u = (u32)u << 16; return x.f;
}

__device__ __forceinline__ unsigned pkbf(float lo, float hi) {
  unsigned r;
  asm("v_cvt_pk_bf16_f32 %0, %1, %2" : "=v"(r) : "v"(lo), "v"(hi));
  return r;
}

__device__ __forceinline__ float expo2(float x) {
#if __has_builtin(__builtin_amdgcn_exp2f)
  return __builtin_amdgcn_exp2f(x);
#else
  return exp2f(x);
#endif
}

#define GLDS16(gp, lp)                                                         \
  __builtin_amdgcn_global_load_lds(                                            \
      (const __attribute__((address_space(1))) void*)(gp),                     \
      (__attribute__((address_space(3))) void*)(lp), 16, 0, 0)

// ---------------- fused prep: 6 weight transposes + x cast, one dispatch ----
__global__ __launch_bounds__(256) void prep_kernel(
    const float* __restrict__ Wq, const float* __restrict__ Wk,
    const float* __restrict__ Wv, const float* __restrict__ Wo,
    const float* __restrict__ W1, const float* __restrict__ W2,
    const float* __restrict__ x, u16* __restrict__ WqT, u16* __restrict__ WoT,
    u16* __restrict__ W1T, u16* __restrict__ W2T, u16* __restrict__ xb) {
  __shared__ float tile[32][33];
  const int id = blockIdx.x;
  if (id < 12288) {
    const float* W; u16* WT; int K, N, bx, by;
    if (id < 4096) {
      const int w = id >> 10, local = id & 1023;
      bx = local & 31; by = local >> 5; K = 1024; N = 1024;
      W = (w == 0) ? Wq : (w == 1) ? Wk : (w == 2) ? Wv : Wo;
      WT = (w == 0) ? WqT : (w == 1) ? WqT + 1048576
           : (w == 2) ? WqT + 2097152 : WoT;
    } else if (id < 8192) {
      const int local = id - 4096;
      bx = local & 127; by = local >> 7; K = 1024; N = 4096;
      W = W1; WT = W1T;
    } else {
      const int local = id - 8192;
      bx = local & 31; by = local >> 5; K = 4096; N = 1024;
      W = W2; WT = W2T;
    }
    const int tx = threadIdx.x & 31, ty = threadIdx.x >> 5;
    const int n0 = bx * 32, k0 = by * 32;
#pragma unroll
    for (int i = 0; i < 4; ++i)
      tile[ty + 8 * i][tx] = W[(size_t)(k0 + ty + 8 * i) * N + n0 + tx];
    __syncthreads();
#pragma unroll
    for (int i = 0; i < 4; ++i)
      WT[(size_t)(n0 + ty + 8 * i) * K + k0 + tx] = f2b(tile[tx][ty + 8 * i]);
  } else {
    const int i = (id - 12288) * 256 + threadIdx.x;
    float4 v = ((const float4*)x)[i];
    ushort4 o;
    o.x = f2b(v.x); o.y = f2b(v.y); o.z = f2b(v.z); o.w = f2b(v.w);
    ((ushort4*)xb)[i] = o;
  }
}

// ---------------- GEMM: C = A[M,K] @ BT[N,K]^T, bf16, dbuf 1-barrier loop ---
template <int MODE, int BN>
__global__ __launch_bounds__(256) void gemmT(
    const u16* __restrict__ A, const u16* __restrict__ BT,
    const float* __restrict__ bias, const float* __restrict__ bias2,
    const float* __restrict__ bias3, const float* __restrict__ res,
    void* __restrict__ outp, const float* __restrict__ kW, int N_, int K_) {
  constexpr int ABYT = 128 * 32 * 2;
  constexpr int BBYT = BN * 32 * 2;
  constexpr int STRIDE = ABYT + BBYT;
  constexpr int MI = (BN == 128) ? 4 : 2;
  __shared__ __align__(16) char SH[2 * STRIDE];
  const int t = threadIdx.x, lane = t & 63, wid = t >> 6;
  const int gx = gridDim.x;
  const int id = blockIdx.y * gx + blockIdx.x;
  const int nb = gx * gridDim.y;
  const int sid = (id & 7) * (nb >> 3) + (id >> 3);
  const int bx = sid % gx;
  int by = sid / gx;
  int kh6 = 0;
  if constexpr (MODE == 6) { kh6 = by >> 5; by &= 31; }
  const int m0 = by * 128, n0 = bx * BN;
  const int wr = (BN == 128) ? (wid >> 1) * 64 : wid * 32;
  const int wc = (BN == 128) ? (wid & 1) * 64 : 0;
  const int lr = lane & 15, lg = lane >> 4;
  const int K = K_;
  const int koff = (MODE == 6) ? kh6 * 1024 : 0;

  f32x4 acc[MI][4] = {};

  const u16* ga0 = A + (size_t)(m0 + (t >> 2)) * K + koff + (t & 3) * 8;
  const u16* ga1 = ga0 + (size_t)64 * K;
  const u16* gb0 = BT + (size_t)(n0 + (t >> 2)) * K + koff + (t & 3) * 8;
  const u16* gb1 = gb0 + (size_t)64 * K;
  const int stA = wid * 1024;

#define STAGE(CUR, KT)                                                         \
  {                                                                            \
    char* l_ = (char*)SH + (CUR) * STRIDE + stA;                               \
    const size_t o_ = (size_t)(KT) * 32;                                       \
    GLDS16(ga0 + o_, l_);                                                      \
    GLDS16(ga1 + o_, l_ + 4096);                                               \
    GLDS16(gb0 + o_, l_ + ABYT);                                               \
    if constexpr (BN == 128) GLDS16(gb1 + o_, l_ + ABYT + 4096);               \
  }

  const int nk = (MODE == 6) ? 32 : (K >> 5);
  STAGE(0, 0);
  __syncthreads();
  int cur = 0;
  for (int kt = 0; kt < nk; ++kt) {
    if (kt + 1 < nk) STAGE(cur ^ 1, kt + 1);
    const char* l = (const char*)SH + cur * STRIDE;
    bf16x8 af[MI], bf[4];
#pragma unroll
    for (int i = 0; i < MI; ++i)
      af[i] = *(const bf16x8*)(l + (wr + i * 16 + lr) * 64 + lg * 16);
#pragma unroll
    for (int i = 0; i < 4; ++i)
      bf[i] = *(const bf16x8*)(l + ABYT + (wc + i * 16 + lr) * 64 + lg * 16);
#pragma unroll
    for (int mi = 0; mi < MI; ++mi)
#pragma unroll
      for (int ni = 0; ni < 4; ++ni)
        acc[mi][ni] = __builtin_amdgcn_mfma_f32_16x16x32_bf16(
            af[mi], bf[ni], acc[mi][ni], 0, 0, 0);
    __syncthreads();
    cur ^= 1;
  }
#undef STAGE

#pragma unroll
  for (int mi = 0; mi < MI; ++mi) {
#pragma unroll
    for (int ni = 0; ni < 4; ++ni) {
      const int row = m0 + wr + mi * 16 + lg * 4;
      const int col = n0 + wc + ni * 16 + lr;
      f32x4 v = acc[mi][ni];
      if constexpr (MODE == 2) {
        const float bv = bias[col];
        u16* o = (u16*)outp;
        const u16* rb = (const u16*)res;
#pragma unroll
        for (int r = 0; r < 4; ++r) {
          const int rr = row + r;
          o[(size_t)rr * N_ + col] =
              f2b(v[r] + bv + b2f(rb[(size_t)rr * N_ + col]));
        }
      } else if constexpr (MODE == 3) {
        const float bv = bias[col];
        u16* o = (u16*)outp;
#pragma unroll
        for (int r = 0; r < 4; ++r) {
          const int rr = row + r;
          float y = v[r] + bv;
          o[(size_t)rr * N_ + col] = f2b(y > 0.f ? y : 0.f);
        }
      } else if constexpr (MODE == 6) {
        u16* o = (kh6 < 2) ? ((u16*)outp + (size_t)kh6 * 4194304)
                           : ((u16*)res + (size_t)(kh6 - 2) * 4194304);
#pragma unroll
        for (int r = 0; r < 4; ++r) {
          const int rr = row + r;
          o[(size_t)rr * N_ + col] = f2b(v[r]);
        }
      } else {  // MODE 5
        const int proj = col >> 10, c = col & 1023;
        const int h = c >> 5, d = c & 31;
        u16* qout = (u16*)outp;
        if (proj == 0) {
          const float bv = bias[c];
          const float sc = kW[d * 32 + h] * 1.44269504089f;
#pragma unroll
          for (int r = 0; r < 4; ++r) {
            const int rr = row + r;
            const int bb = rr >> 11, s = rr & 2047;
            qout[(size_t)(((bb * 32 + h) * 2048) + s) * 32 + d] =
                f2b((v[r] + bv) * sc);
          }
        } else if (proj == 1) {
          const float bv = bias2[c];
          u16* kout = qout + 4194304;
          const int c2 = d >> 3;
#pragma unroll
          for (int r = 0; r < 4; ++r) {
            const int rr = row + r;
            const int bb = rr >> 11, s = rr & 2047;
            const int k = s & 63;
            const int g = ((k >> 5) << 1) | (c2 >> 1);
            kout[(size_t)(bb * 32 + h) * 65536 + (s >> 6) * 2048 + g * 512 +
                 (c2 & 1) * 256 + (k & 31) * 8 + (d & 7)] = f2b(v[r] + bv);
          }
        } else {
          const float bv = bias3[c];
          u16* vout = qout + 8388608;
          const int bb = row >> 11, s0 = row & 2047;
          const int k = s0 & 63;
          const int cc = k >> 3, rb = cc >> 1, hb = cc & 1, e = k & 7;
          ushort4 st;
          st.x = f2b(v[0] + bv); st.y = f2b(v[1] + bv);
          st.z = f2b(v[2] + bv); st.w = f2b(v[3] + bv);
          *(ushort4*)(vout + (size_t)(bb * 32 + h) * 65536 +
                      (s0 >> 6) * 2048 + rb * 512 + hb * 256 + d * 8 + e) = st;
        }
      }
    }
  }
}

// ---------------- attention tile compute (64 keys) --------------------------
__device__ __forceinline__ void attn_tile(
    const bf16x8& k0, const bf16x8& k1, const bf16x8& k2, const bf16x8& k3,
    const bf16x8& v0, const bf16x8& v1, const bf16x8& v2, const bf16x8& v3,
    const bf16x8& qb0, const bf16x8& qb1,
    f32x16& acc, float& la, float& lb, float& lc, float& ld) {
  const f32x16 z16 = {};
  f32x16 s0 = __builtin_amdgcn_mfma_f32_32x32x16_bf16(k0, qb0, z16, 0, 0, 0);
  s0 = __builtin_amdgcn_mfma_f32_32x32x16_bf16(k1, qb1, s0, 0, 0, 0);
  f32x16 s1 = __builtin_amdgcn_mfma_f32_32x32x16_bf16(k2, qb0, z16, 0, 0, 0);
  s1 = __builtin_amdgcn_mfma_f32_32x32x16_bf16(k3, qb1, s1, 0, 0, 0);
  float p0[16], p1[16];
#pragma unroll
  for (int r = 0; r < 16; ++r) p0[r] = expo2(s0[r]);
#pragma unroll
  for (int r = 0; r < 16; ++r) p1[r] = expo2(s1[r]);
#pragma unroll
  for (int r = 0; r < 4; ++r) {
    la += p0[r] + p1[r];
    lb += p0[4 + r] + p1[4 + r];
    lc += p0[8 + r] + p1[8 + r];
    ld += p0[12 + r] + p1[12 + r];
  }
  {
    u32 x0 = pkbf(p0[0], p0[1]), x1 = pkbf(p0[2], p0[3]);
    u32 y0 = pkbf(p0[4], p0[5]), y1 = pkbf(p0[6], p0[7]);
    asm("v_permlane32_swap_b32 %0, %1" : "+v"(x0), "+v"(y0));
    asm("v_permlane32_swap_b32 %0, %1" : "+v"(x1), "+v"(y1));
    union { u32 d[4]; bf16x8 v; } u;
    u.d[0] = x0; u.d[1] = x1; u.d[2] = y0; u.d[3] = y1;
    acc = __builtin_amdgcn_mfma_f32_32x32x16_bf16(v0, u.v, acc, 0, 0, 0);
  }
  {
    u32 x0 = pkbf(p0[8], p0[9]), x1 = pkbf(p0[10], p0[11]);
    u32 y0 = pkbf(p0[12], p0[13]), y1 = pkbf(p0[14], p0[15]);
    asm("v_permlane32_swap_b32 %0, %1" : "+v"(x0), "+v"(y0));
    asm("v_permlane32_swap_b32 %0, %1" : "+v"(x1), "+v"(y1));
    union { u32 d[4]; bf16x8 v; } u;
    u.d[0] = x0; u.d[1] = x1; u.d[2] = y0; u.d[3] = y1;
    acc = __builtin_amdgcn_mfma_f32_32x32x16_bf16(v1, u.v, acc, 0, 0, 0);
  }
  {
    u32 x0 = pkbf(p1[0], p1[1]), x1 = pkbf(p1[2], p1[3]);
    u32 y0 = pkbf(p1[4], p1[5]), y1 = pkbf(p1[6], p1[7]);
    asm("v_permlane32_swap_b32 %0, %1" : "+v"(x0), "+v"(y0));
    asm("v_permlane32_swap_b32 %0, %1" : "+v"(x1), "+v"(y1));
    union { u32 d[4]; bf16x8 v; } u;
    u.d[0] = x0; u.d[1] = x1; u.d[2] = y0; u.d[3] = y1;
    acc = __builtin_amdgcn_mfma_f32_32x32x16_bf16(v2, u.v, acc, 0, 0, 0);
  }
  {
    u32 x0 = pkbf(p1[8], p1[9]), x1 = pkbf(p1[10], p1[11]);
    u32 y0 = pkbf(p1[12], p1[13]), y1 = pkbf(p1[14], p1[15]);
    asm("v_permlane32_swap_b32 %0, %1" : "+v"(x0), "+v"(y0));
    asm("v_permlane32_swap_b32 %0, %1" : "+v"(x1), "+v"(y1));
    union { u32 d[4]; bf16x8 v; } u;
    u.d[0] = x0; u.d[1] = x1; u.d[2] = y0; u.d[3] = y1;
    acc = __builtin_amdgcn_mfma_f32_32x32x16_bf16(v3, u.v, acc, 0, 0, 0);
  }
}

// ---------------- attention: 3-buffer pipelined LDS staging, 8 waves --------
// Block = 8 waves: qg = wid&3 (32 queries, 128 total), kh = wid>>2.
// Pipeline: loads for tile i issued at iter i-2; per-iter wait = vmcnt(8)
// (tile i's loads long landed); raw s_barrier x2 per iter, NO vmcnt(0) drain.
// Slot reuse ledger: iter-top barrier keeps waves <=1 iter apart; slot
// (i+2)%3 holds tile i-1, whose reads finished before that barrier.
__global__ __launch_bounds__(512) void attn_kernel(
    const u16* __restrict__ Q, const u16* __restrict__ K,
    const u16* __restrict__ VT, u16* __restrict__ O) {
  __shared__ __align__(16) char LDSB[49152];
  const int t = threadIdx.x, wid = t >> 6, lane = t & 63;
  const int qg = wid & 3, kh = wid >> 2;
  const int bid = blockIdx.x;                    // 1024 blocks
  const int swz = (bid & 7) * 128 + (bid >> 3);  // 8 XCDs
  const int bh = swz >> 4;                       // 0..63
  const int qt = swz & 15;                       // q-tile of 128
  const int q0 = qt * 128 + qg * 32;
  const int lq = lane & 31, hi = lane >> 5;
  const u16* Qh = Q + (size_t)bh * 65536;
  const u16* Kh = K + (size_t)bh * 65536;
  const u16* Vh = VT + (size_t)bh * 65536;

  const bf16x8 qb0 = *(const bf16x8*)(Qh + (size_t)(q0 + lq) * 32 + hi * 8);
  const bf16x8 qb1 = *(const bf16x8*)(Qh + (size_t)(q0 + lq) * 32 + 16 + hi * 8);

  const u16* kg = Kh + wid * 512 + lane * 8;
  const u16* vg = Vh + wid * 512 + lane * 8;
  const int lds_w = wid * 1024;

#define STAGEA(SLOT, I)                                                        \
  if (wid < 4) {                                                               \
    char* b_ = LDSB + (SLOT) * 16384 + lds_w;                                  \
    GLDS16(kg + (size_t)(I) * 2048, b_);                                       \
    GLDS16(vg + (size_t)(I) * 2048, b_ + 4096);                                \
    GLDS16(kg + (size_t)(16 + (I)) * 2048, b_ + 8192);                         \
    GLDS16(vg + (size_t)(16 + (I)) * 2048, b_ + 12288);                        \
  }

#define COMPUTE(SLOT)                                                          \
  {                                                                            \
    const char* kb = LDSB + (SLOT) * 16384 + kh * 8192 + lane * 16;            \
    const bf16x8 ka0 = *(const bf16x8*)(kb);                                   \
    const bf16x8 ka1 = *(const bf16x8*)(kb + 1024);                            \
    const bf16x8 ka2 = *(const bf16x8*)(kb + 2048);                            \
    const bf16x8 ka3 = *(const bf16x8*)(kb + 3072);                            \
    const bf16x8 va0 = *(const bf16x8*)(kb + 4096);                            \
    const bf16x8 va1 = *(const bf16x8*)(kb + 5120);                            \
    const bf16x8 va2 = *(const bf16x8*)(kb + 6144);                            \
    const bf16x8 va3 = *(const bf16x8*)(kb + 7168);                            \
    attn_tile(ka0, ka1, ka2, ka3, va0, va1, va2, va3, qb0, qb1,                \
              acc, la, lb, lc, ld);                                            \
  }

  f32x16 acc = {};
  float la = 0.f, lb = 0.f, lc = 0.f, ld = 0.f;

  STAGEA(0, 0);
  STAGEA(1, 1);
#pragma unroll 1
  for (int i = 0; i < 14; ++i) {
    __builtin_amdgcn_s_barrier();
    STAGEA((i + 2) % 3, i + 2);
    asm volatile("s_waitcnt vmcnt(8)" ::: "memory");
    __builtin_amdgcn_s_barrier();
    COMPUTE(i % 3);
  }
  // i = 14 (slot 2): tile 15 still in flight -> vmcnt(4)
  __builtin_amdgcn_s_barrier();
  asm volatile("s_waitcnt vmcnt(4)" ::: "memory");
  __builtin_amdgcn_s_barrier();
  COMPUTE(2);
  // i = 15 (slot 0): drain
  __builtin_amdgcn_s_barrier();
  asm volatile("s_waitcnt vmcnt(0)" ::: "memory");
  __builtin_amdgcn_s_barrier();
  COMPUTE(0);
#undef STAGEA
#undef COMPUTE

  float lrun = (la + lb) + (lc + ld);
  lrun += __shfl_xor(lrun, 32);

  __syncthreads();  // all tile reads done before merge scratch reuse
  // merge scratch in slots 1-2 (tiles 13/14, dead)
  float* sm_acc = (float*)(LDSB + 16384);  // [4][64][16] = 16KB
  float* sm_l = (float*)(LDSB + 32768);    // [4][32]
  if (kh == 1) {
    sm_l[qg * 32 + lq] = lrun;
#pragma unroll
    for (int r = 0; r < 16; ++r) sm_acc[(qg * 64 + lane) * 16 + r] = acc[r];
  }
  __syncthreads();
  if (kh == 0) {
    const float inv = 1.f / (lrun + sm_l[qg * 32 + lq]);
    const int bb = bh >> 5, h = bh & 31;
    u16* o = O + (size_t)(bb * 2048 + q0 + lq) * 1024 + h * 32;
#pragma unroll
    for (int g = 0; g < 4; ++g) {
      ushort4 st;
      st.x = f2b((acc[g * 4 + 0] + sm_acc[(qg * 64 + lane) * 16 + g * 4 + 0]) * inv);
      st.y = f2b((acc[g * 4 + 1] + sm_acc[(qg * 64 + lane) * 16 + g * 4 + 1]) * inv);
      st.z = f2b((acc[g * 4 + 2] + sm_acc[(qg * 64 + lane) * 16 + g * 4 + 2]) * inv);
      st.w = f2b((acc[g * 4 + 3] + sm_acc[(qg * 64 + lane) * 16 + g * 4 + 3]) * inv);
      *(ushort4*)(o + g * 8 + hi * 4) = st;
    }
  }
}

// ---------------- LN1 in-place on bf16 r1b ----------------------------------
__global__ __launch_bounds__(256) void ln1b_kernel(
    u16* __restrict__ X, const float* __restrict__ g,
    const float* __restrict__ b) {
  const int wid = threadIdx.x >> 6, lane = threadIdx.x & 63;
  const int row = blockIdx.x * 4 + wid;
  ushort4* X4 = (ushort4*)(X + (size_t)row * 1024);
  float4 xs[4];
  float s = 0.f, sq = 0.f;
#pragma unroll
  for (int i = 0; i < 4; ++i) {
    const ushort4 u = X4[lane + i * 64];
    float4 v;
    v.x = b2f(u.x); v.y = b2f(u.y); v.z = b2f(u.z); v.w = b2f(u.w);
    xs[i] = v;
    s += v.x + v.y + v.z + v.w;
    sq += v.x * v.x + v.y * v.y + v.z * v.z + v.w * v.w;
  }
#pragma unroll
  for (int m = 1; m < 64; m <<= 1) { s += __shfl_xor(s, m); sq += __shfl_xor(sq, m); }
  const float mean = s * (1.f / 1024.f);
  float var = sq * (1.f / 1024.f) - mean * mean;
  var = var > 0.f ? var : 0.f;
  const float rstd = rsqrtf(var + 1e-5f);
  const float4* g4 = (const float4*)g;
  const float4* b4 = (const float4*)b;
#pragma unroll
  for (int i = 0; i < 4; ++i) {
    const int c = lane + i * 64;
    const float4 gv = g4[c], bv = b4[c], x = xs[i];
    ushort4 yb;
    yb.x = f2b((x.x - mean) * rstd * gv.x + bv.x);
    yb.y = f2b((x.y - mean) * rstd * gv.y + bv.y);
    yb.z = f2b((x.z - mean) * rstd * gv.z + bv.z);
    yb.w = f2b((x.w - mean) * rstd * gv.w + bv.w);
    X4[c] = yb;
  }
}

// ---------------- LN2: x = p0+p1+p2+p3 (bf16) + res(bf16) + bias ------------
__global__ __launch_bounds__(256) void ln2sum_kernel(
    const u16* __restrict__ P0, const u16* __restrict__ P1,
    const u16* __restrict__ P2, const u16* __restrict__ P3,
    const u16* __restrict__ R, const float* __restrict__ bias,
    const float* __restrict__ g, const float* __restrict__ b,
    float* __restrict__ out) {
  const int wid = threadIdx.x >> 6, lane = threadIdx.x & 63;
  const int row = blockIdx.x * 4 + wid;
  const ushort4* A4 = (const ushort4*)(P0 + (size_t)row * 1024);
  const ushort4* B4 = (const ushort4*)(P1 + (size_t)row * 1024);
  const ushort4* C4 = (const ushort4*)(P2 + (size_t)row * 1024);
  const ushort4* D4 = (const ushort4*)(P3 + (size_t)row * 1024);
  const ushort4* R4 = (const ushort4*)(R + (size_t)row * 1024);
  const float4* Bi4 = (const float4*)bias;
  float4 xs[4];
  float s = 0.f, sq = 0.f;
#pragma unroll
  for (int i = 0; i < 4; ++i) {
    const int c = lane + i * 64;
    const ushort4 a = A4[c], pb = B4[c], pc = C4[c], pd = D4[c], rr = R4[c];
    const float4 bi = Bi4[c];
    float4 x;
    x.x = (b2f(a.x) + b2f(pb.x)) + (b2f(pc.x) + b2f(pd.x)) + b2f(rr.x) + bi.x;
    x.y = (b2f(a.y) + b2f(pb.y)) + (b2f(pc.y) + b2f(pd.y)) + b2f(rr.y) + bi.y;
    x.z = (b2f(a.z) + b2f(pb.z)) + (b2f(pc.z) + b2f(pd.z)) + b2f(rr.z) + bi.z;
    x.w = (b2f(a.w) + b2f(pb.w)) + (b2f(pc.w) + b2f(pd.w)) + b2f(rr.w) + bi.w;
    xs[i] = x;
    s += x.x + x.y + x.z + x.w;
    sq += x.x * x.x + x.y * x.y + x.z * x.z + x.w * x.w;
  }
#pragma unroll
  for (int m = 1; m < 64; m <<= 1) { s += __shfl_xor(s, m); sq += __shfl_xor(sq, m); }
  const float mean = s * (1.f / 1024.f);
  float var = sq * (1.f / 1024.f) - mean * mean;
  var = var > 0.f ? var : 0.f;
  const float rstd = rsqrtf(var + 1e-5f);
  const float4* g4 = (const float4*)g;
  const float4* b4 = (const float4*)b;
  float4* of = (float4*)(out + (size_t)row * 1024);
#pragma unroll
  for (int i = 0; i < 4; ++i) {
    const int c = lane + i * 64;
    const float4 gv = g4[c], bv = b4[c], x = xs[i];
    float4 y;
    y.x = (x.x - mean) * rstd * gv.x + bv.x;
    y.y = (x.y - mean) * rstd * gv.y + bv.y;
    y.z = (x.z - mean) * rstd * gv.z + bv.z;
    y.w = (x.w - mean) * rstd * gv.w + bv.w;
    of[c] = y;
  }
}

// ---------------------------------------------------------------------------
extern "C" void kernel_launch(void* const* d_in, const int* in_sizes, int n_in,
                              void* d_out, int out_size, void* d_ws,
                              size_t ws_size, hipStream_t stream) {
  const float* x   = (const float*)d_in[0];
  const float* Wq  = (const float*)d_in[1];
  const float* bq  = (const float*)d_in[2];
  const float* Wk  = (const float*)d_in[3];
  const float* bk  = (const float*)d_in[4];
  const float* Wv  = (const float*)d_in[5];
  const float* bv  = (const float*)d_in[6];
  const float* kW  = (const float*)d_in[7];
  const float* Wo  = (const float*)d_in[8];
  const float* bo  = (const float*)d_in[9];
  const float* W1  = (const float*)d_in[10];
  const float* b1  = (const float*)d_in[11];
  const float* W2  = (const float*)d_in[12];
  const float* b2  = (const float*)d_in[13];
  const float* g1  = (const float*)d_in[14];
  const float* be1 = (const float*)d_in[15];
  const float* g2  = (const float*)d_in[16];
  const float* be2 = (const float*)d_in[17];

  char* ws = (char*)d_ws;
  const size_t MB = 1024 * 1024;
  u16*   WqT = (u16*)(ws + 0 * MB);   // [0,6) = fused QKV BT[3072][1024]
  u16*   WoT = (u16*)(ws + 6 * MB);
  u16*   W1T = (u16*)(ws + 8 * MB);
  u16*   W2T = (u16*)(ws + 16 * MB);
  u16*   r1b = (u16*)(ws + 24 * MB);  // bf16 residual stream [24,32)
  u16*   xb  = (u16*)(ws + 40 * MB);
  u16*   qhB = (u16*)(ws + 48 * MB);
  u16*   khB = (u16*)(ws + 56 * MB);
  u16*   vTB = (u16*)(ws + 64 * MB);
  u16*   hf  = (u16*)(ws + 40 * MB);  // FFN1 out, aliases xb..vT (dead)
  u16*   ao  = (u16*)(ws + 72 * MB);
  u16*   p0  = (u16*)(ws + 0 * MB);   // FFN2 bf16 partials (dead regions)
  u16*   p2  = (u16*)(ws + 72 * MB);

  const dim3 blk(256);

  prep_kernel<<<16384, blk, 0, stream>>>(Wq, Wk, Wv, Wo, W1, W2, x,
                                         WqT, WoT, W1T, W2T, xb);

  gemmT<5, 128><<<dim3(24, 32), blk, 0, stream>>>(
      xb, WqT, bq, bk, bv, nullptr, qhB, kW, 3072, 1024);

  attn_kernel<<<1024, dim3(512), 0, stream>>>(qhB, khB, vTB, ao);

  gemmT<2, 64><<<dim3(16, 32), blk, 0, stream>>>(
      ao, WoT, bo, nullptr, nullptr, (const float*)xb, r1b, nullptr,
      1024, 1024);
  ln1b_kernel<<<1024, blk, 0, stream>>>(r1b, g1, be1);
  gemmT<3, 128><<<dim3(32, 32), blk, 0, stream>>>(
      r1b, W1T, b1, nullptr, nullptr, nullptr, hf, nullptr, 4096, 1024);
  gemmT<6, 128><<<dim3(8, 128), blk, 0, stream>>>(
      hf, W2T, nullptr, nullptr, nullptr, (const float*)p2, p0, nullptr,
      1024, 4096);
  ln2sum_kernel<<<1024, blk, 0, stream>>>(p0, p0 + 4194304, p2, p2 + 4194304,
                                          r1b, b2, g2, be2, (float*)d_out);

  (void)in_sizes; (void)n_in; (void)out_size; (void)ws_size;
}

// Round 16
// 235.584 us; speedup vs baseline: 1.0064x; 1.0064x over previous
//
#include <hip/hip_runtime.h>

// ---------------------------------------------------------------------------
// TransformerBlockQuantum: B=2,S=2048,E=1024,H=32,DK=32,FFN=4096
// GEMMs: bf16 MFMA 16x16x32, LDS dbuf single-barrier loop, XCD swizzle.
// Wo = BN=128 split-K 2-way bf16 partials (merged in ln1merge).
// FFN2 = BN=128 split-K 4-way bf16 partials (merged in ln2sum).
// Attention: round-14 exact (8-wave LDS-staged dbuf). Prep fused.
// ws layout (MB):
//  [0,6) QKV BT  [6,8)WoT [8,16)W1T [16,24)W2T
//  [24,32) r1b (bf16)   [40,72) xb/qh/kh/vT then hf   [72,88) ao
//  Wo partials: pw0[48,56) pw1[56,64) (qh/kh dead after attn)
//  FFN2 partials: p0[0,8) p1[8,16) p2[72,80) p3[80,88) (dead by then)
// ---------------------------------------------------------------------------

typedef unsigned short u16;
typedef unsigned int u32;
typedef __bf16 bf16x8 __attribute__((ext_vector_type(8)));
typedef float f32x4 __attribute__((ext_vector_type(4)));
typedef float f32x16 __attribute__((ext_vector_type(16)));

__device__ __forceinline__ u16 f2b(float f) {
  union { float f; unsigned u; } x; x.f = f;
  unsigned r = x.u + 0x7FFFu + ((x.u >> 16) & 1u);
  return (u16)(r >> 16);
}

__device__ __forceinline__ float b2f(u16 u) {
  union { u32 u; float f; } x; x.u = (u32)u << 16; return x.f;
}

__device__ __forceinline__ unsigned pkbf(float lo, float hi) {
  unsigned r;
  asm("v_cvt_pk_bf16_f32 %0, %1, %2" : "=v"(r) : "v"(lo), "v"(hi));
  return r;
}

__device__ __forceinline__ float expo2(float x) {
#if __has_builtin(__builtin_amdgcn_exp2f)
  return __builtin_amdgcn_exp2f(x);
#else
  return exp2f(x);
#endif
}

#define GLDS16(gp, lp)                                                         \
  __builtin_amdgcn_global_load_lds(                                            \
      (const __attribute__((address_space(1))) void*)(gp),                     \
      (__attribute__((address_space(3))) void*)(lp), 16, 0, 0)

// ---------------- fused prep: 6 weight transposes + x cast, one dispatch ----
__global__ __launch_bounds__(256) void prep_kernel(
    const float* __restrict__ Wq, const float* __restrict__ Wk,
    const float* __restrict__ Wv, const float* __restrict__ Wo,
    const float* __restrict__ W1, const float* __restrict__ W2,
    const float* __restrict__ x, u16* __restrict__ WqT, u16* __restrict__ WoT,
    u16* __restrict__ W1T, u16* __restrict__ W2T, u16* __restrict__ xb) {
  __shared__ float tile[32][33];
  const int id = blockIdx.x;
  if (id < 12288) {
    const float* W; u16* WT; int K, N, bx, by;
    if (id < 4096) {
      const int w = id >> 10, local = id & 1023;
      bx = local & 31; by = local >> 5; K = 1024; N = 1024;
      W = (w == 0) ? Wq : (w == 1) ? Wk : (w == 2) ? Wv : Wo;
      WT = (w == 0) ? WqT : (w == 1) ? WqT + 1048576
           : (w == 2) ? WqT + 2097152 : WoT;
    } else if (id < 8192) {
      const int local = id - 4096;
      bx = local & 127; by = local >> 7; K = 1024; N = 4096;
      W = W1; WT = W1T;
    } else {
      const int local = id - 8192;
      bx = local & 31; by = local >> 5; K = 4096; N = 1024;
      W = W2; WT = W2T;
    }
    const int tx = threadIdx.x & 31, ty = threadIdx.x >> 5;
    const int n0 = bx * 32, k0 = by * 32;
#pragma unroll
    for (int i = 0; i < 4; ++i)
      tile[ty + 8 * i][tx] = W[(size_t)(k0 + ty + 8 * i) * N + n0 + tx];
    __syncthreads();
#pragma unroll
    for (int i = 0; i < 4; ++i)
      WT[(size_t)(n0 + ty + 8 * i) * K + k0 + tx] = f2b(tile[tx][ty + 8 * i]);
  } else {
    const int i = (id - 12288) * 256 + threadIdx.x;
    float4 v = ((const float4*)x)[i];
    ushort4 o;
    o.x = f2b(v.x); o.y = f2b(v.y); o.z = f2b(v.z); o.w = f2b(v.w);
    ((ushort4*)xb)[i] = o;
  }
}

// ---------------- GEMM: C = A[M,K] @ BT[N,K]^T, bf16, dbuf 1-barrier loop ---
// MODE 3: bf16 out = relu(acc + bias)
// MODE 5: fused QKV epilogues (q-scaled head / k,v fragment-order tiles)
// MODE 6: split-K 4-way (by>>5), bf16 partial -> 4 bufs (outp, res bases)
// MODE 7: split-K 2-way (by>>5), bf16 partial -> outp (kh=0) / res (kh=1)
template <int MODE, int BN>
__global__ __launch_bounds__(256) void gemmT(
    const u16* __restrict__ A, const u16* __restrict__ BT,
    const float* __restrict__ bias, const float* __restrict__ bias2,
    const float* __restrict__ bias3, const float* __restrict__ res,
    void* __restrict__ outp, const float* __restrict__ kW, int N_, int K_) {
  constexpr int ABYT = 128 * 32 * 2;
  constexpr int BBYT = BN * 32 * 2;
  constexpr int STRIDE = ABYT + BBYT;
  constexpr int MI = (BN == 128) ? 4 : 2;
  __shared__ __align__(16) char SH[2 * STRIDE];
  const int t = threadIdx.x, lane = t & 63, wid = t >> 6;
  const int gx = gridDim.x;
  const int id = blockIdx.y * gx + blockIdx.x;
  const int nb = gx * gridDim.y;
  const int sid = (id & 7) * (nb >> 3) + (id >> 3);
  const int bx = sid % gx;
  int by = sid / gx;
  int kh6 = 0;
  if constexpr (MODE == 6 || MODE == 7) { kh6 = by >> 5; by &= 31; }
  const int m0 = by * 128, n0 = bx * BN;
  const int wr = (BN == 128) ? (wid >> 1) * 64 : wid * 32;
  const int wc = (BN == 128) ? (wid & 1) * 64 : 0;
  const int lr = lane & 15, lg = lane >> 4;
  const int K = K_;
  const int koff = (MODE == 6) ? kh6 * 1024 : (MODE == 7) ? kh6 * 512 : 0;

  f32x4 acc[MI][4] = {};

  const u16* ga0 = A + (size_t)(m0 + (t >> 2)) * K + koff + (t & 3) * 8;
  const u16* ga1 = ga0 + (size_t)64 * K;
  const u16* gb0 = BT + (size_t)(n0 + (t >> 2)) * K + koff + (t & 3) * 8;
  const u16* gb1 = gb0 + (size_t)64 * K;
  const int stA = wid * 1024;

#define STAGE(CUR, KT)                                                         \
  {                                                                            \
    char* l_ = (char*)SH + (CUR) * STRIDE + stA;                               \
    const size_t o_ = (size_t)(KT) * 32;                                       \
    GLDS16(ga0 + o_, l_);                                                      \
    GLDS16(ga1 + o_, l_ + 4096);                                               \
    GLDS16(gb0 + o_, l_ + ABYT);                                               \
    if constexpr (BN == 128) GLDS16(gb1 + o_, l_ + ABYT + 4096);               \
  }

  const int nk = (MODE == 6) ? 32 : (MODE == 7) ? 16 : (K >> 5);
  STAGE(0, 0);
  __syncthreads();
  int cur = 0;
  for (int kt = 0; kt < nk; ++kt) {
    if (kt + 1 < nk) STAGE(cur ^ 1, kt + 1);
    const char* l = (const char*)SH + cur * STRIDE;
    bf16x8 af[MI], bf[4];
#pragma unroll
    for (int i = 0; i < MI; ++i)
      af[i] = *(const bf16x8*)(l + (wr + i * 16 + lr) * 64 + lg * 16);
#pragma unroll
    for (int i = 0; i < 4; ++i)
      bf[i] = *(const bf16x8*)(l + ABYT + (wc + i * 16 + lr) * 64 + lg * 16);
#pragma unroll
    for (int mi = 0; mi < MI; ++mi)
#pragma unroll
      for (int ni = 0; ni < 4; ++ni)
        acc[mi][ni] = __builtin_amdgcn_mfma_f32_16x16x32_bf16(
            af[mi], bf[ni], acc[mi][ni], 0, 0, 0);
    __syncthreads();
    cur ^= 1;
  }
#undef STAGE

#pragma unroll
  for (int mi = 0; mi < MI; ++mi) {
#pragma unroll
    for (int ni = 0; ni < 4; ++ni) {
      const int row = m0 + wr + mi * 16 + lg * 4;
      const int col = n0 + wc + ni * 16 + lr;
      f32x4 v = acc[mi][ni];
      if constexpr (MODE == 3) {
        const float bv = bias[col];
        u16* o = (u16*)outp;
#pragma unroll
        for (int r = 0; r < 4; ++r) {
          const int rr = row + r;
          float y = v[r] + bv;
          o[(size_t)rr * N_ + col] = f2b(y > 0.f ? y : 0.f);
        }
      } else if constexpr (MODE == 6) {
        u16* o = (kh6 < 2) ? ((u16*)outp + (size_t)kh6 * 4194304)
                           : ((u16*)res + (size_t)(kh6 - 2) * 4194304);
#pragma unroll
        for (int r = 0; r < 4; ++r) {
          const int rr = row + r;
          o[(size_t)rr * N_ + col] = f2b(v[r]);
        }
      } else if constexpr (MODE == 7) {
        u16* o = (kh6 == 0) ? (u16*)outp : (u16*)res;
#pragma unroll
        for (int r = 0; r < 4; ++r) {
          const int rr = row + r;
          o[(size_t)rr * N_ + col] = f2b(v[r]);
        }
      } else {  // MODE 5
        const int proj = col >> 10, c = col & 1023;
        const int h = c >> 5, d = c & 31;
        u16* qout = (u16*)outp;
        if (proj == 0) {
          const float bv = bias[c];
          const float sc = kW[d * 32 + h] * 1.44269504089f;
#pragma unroll
          for (int r = 0; r < 4; ++r) {
            const int rr = row + r;
            const int bb = rr >> 11, s = rr & 2047;
            qout[(size_t)(((bb * 32 + h) * 2048) + s) * 32 + d] =
                f2b((v[r] + bv) * sc);
          }
        } else if (proj == 1) {
          const float bv = bias2[c];
          u16* kout = qout + 4194304;
          const int c2 = d >> 3;
#pragma unroll
          for (int r = 0; r < 4; ++r) {
            const int rr = row + r;
            const int bb = rr >> 11, s = rr & 2047;
            const int k = s & 63;
            const int g = ((k >> 5) << 1) | (c2 >> 1);
            kout[(size_t)(bb * 32 + h) * 65536 + (s >> 6) * 2048 + g * 512 +
                 (c2 & 1) * 256 + (k & 31) * 8 + (d & 7)] = f2b(v[r] + bv);
          }
        } else {
          const float bv = bias3[c];
          u16* vout = qout + 8388608;
          const int bb = row >> 11, s0 = row & 2047;
          const int k = s0 & 63;
          const int cc = k >> 3, rb = cc >> 1, hb = cc & 1, e = k & 7;
          ushort4 st;
          st.x = f2b(v[0] + bv); st.y = f2b(v[1] + bv);
          st.z = f2b(v[2] + bv); st.w = f2b(v[3] + bv);
          *(ushort4*)(vout + (size_t)(bb * 32 + h) * 65536 +
                      (s0 >> 6) * 2048 + rb * 512 + hb * 256 + d * 8 + e) = st;
        }
      }
    }
  }
}

// ---------------- attention tile compute (64 keys) --------------------------
__device__ __forceinline__ void attn_tile(
    const bf16x8& k0, const bf16x8& k1, const bf16x8& k2, const bf16x8& k3,
    const bf16x8& v0, const bf16x8& v1, const bf16x8& v2, const bf16x8& v3,
    const bf16x8& qb0, const bf16x8& qb1,
    f32x16& acc, float& la, float& lb, float& lc, float& ld) {
  const f32x16 z16 = {};
  f32x16 s0 = __builtin_amdgcn_mfma_f32_32x32x16_bf16(k0, qb0, z16, 0, 0, 0);
  s0 = __builtin_amdgcn_mfma_f32_32x32x16_bf16(k1, qb1, s0, 0, 0, 0);
  f32x16 s1 = __builtin_amdgcn_mfma_f32_32x32x16_bf16(k2, qb0, z16, 0, 0, 0);
  s1 = __builtin_amdgcn_mfma_f32_32x32x16_bf16(k3, qb1, s1, 0, 0, 0);
  float p0[16], p1[16];
#pragma unroll
  for (int r = 0; r < 16; ++r) p0[r] = expo2(s0[r]);
#pragma unroll
  for (int r = 0; r < 16; ++r) p1[r] = expo2(s1[r]);
#pragma unroll
  for (int r = 0; r < 4; ++r) {
    la += p0[r] + p1[r];
    lb += p0[4 + r] + p1[4 + r];
    lc += p0[8 + r] + p1[8 + r];
    ld += p0[12 + r] + p1[12 + r];
  }
  {
    u32 x0 = pkbf(p0[0], p0[1]), x1 = pkbf(p0[2], p0[3]);
    u32 y0 = pkbf(p0[4], p0[5]), y1 = pkbf(p0[6], p0[7]);
    asm("v_permlane32_swap_b32 %0, %1" : "+v"(x0), "+v"(y0));
    asm("v_permlane32_swap_b32 %0, %1" : "+v"(x1), "+v"(y1));
    union { u32 d[4]; bf16x8 v; } u;
    u.d[0] = x0; u.d[1] = x1; u.d[2] = y0; u.d[3] = y1;
    acc = __builtin_amdgcn_mfma_f32_32x32x16_bf16(v0, u.v, acc, 0, 0, 0);
  }
  {
    u32 x0 = pkbf(p0[8], p0[9]), x1 = pkbf(p0[10], p0[11]);
    u32 y0 = pkbf(p0[12], p0[13]), y1 = pkbf(p0[14], p0[15]);
    asm("v_permlane32_swap_b32 %0, %1" : "+v"(x0), "+v"(y0));
    asm("v_permlane32_swap_b32 %0, %1" : "+v"(x1), "+v"(y1));
    union { u32 d[4]; bf16x8 v; } u;
    u.d[0] = x0; u.d[1] = x1; u.d[2] = y0; u.d[3] = y1;
    acc = __builtin_amdgcn_mfma_f32_32x32x16_bf16(v1, u.v, acc, 0, 0, 0);
  }
  {
    u32 x0 = pkbf(p1[0], p1[1]), x1 = pkbf(p1[2], p1[3]);
    u32 y0 = pkbf(p1[4], p1[5]), y1 = pkbf(p1[6], p1[7]);
    asm("v_permlane32_swap_b32 %0, %1" : "+v"(x0), "+v"(y0));
    asm("v_permlane32_swap_b32 %0, %1" : "+v"(x1), "+v"(y1));
    union { u32 d[4]; bf16x8 v; } u;
    u.d[0] = x0; u.d[1] = x1; u.d[2] = y0; u.d[3] = y1;
    acc = __builtin_amdgcn_mfma_f32_32x32x16_bf16(v2, u.v, acc, 0, 0, 0);
  }
  {
    u32 x0 = pkbf(p1[8], p1[9]), x1 = pkbf(p1[10], p1[11]);
    u32 y0 = pkbf(p1[12], p1[13]), y1 = pkbf(p1[14], p1[15]);
    asm("v_permlane32_swap_b32 %0, %1" : "+v"(x0), "+v"(y0));
    asm("v_permlane32_swap_b32 %0, %1" : "+v"(x1), "+v"(y1));
    union { u32 d[4]; bf16x8 v; } u;
    u.d[0] = x0; u.d[1] = x1; u.d[2] = y0; u.d[3] = y1;
    acc = __builtin_amdgcn_mfma_f32_32x32x16_bf16(v3, u.v, acc, 0, 0, 0);
  }
}

// ---------------- swapped 32x32 flash attention, LDS-staged, 8 waves --------
// (round-14 exact)
__global__ __launch_bounds__(512) void attn_kernel(
    const u16* __restrict__ Q, const u16* __restrict__ K,
    const u16* __restrict__ VT, u16* __restrict__ O) {
  __shared__ __align__(16) char LDSB[32768];
  const int t = threadIdx.x, wid = t >> 6, lane = t & 63;
  const int qg = wid & 3, kh = wid >> 2;
  const int bid = blockIdx.x;                    // 1024 blocks
  const int swz = (bid & 7) * 128 + (bid >> 3);  // 8 XCDs
  const int bh = swz >> 4;                       // 0..63
  const int qt = swz & 15;                       // q-tile of 128
  const int q0 = qt * 128 + qg * 32;
  const int lq = lane & 31, hi = lane >> 5;
  const u16* Qh = Q + (size_t)bh * 65536;
  const u16* Kh = K + (size_t)bh * 65536;
  const u16* Vh = VT + (size_t)bh * 65536;

  const bf16x8 qb0 = *(const bf16x8*)(Qh + (size_t)(q0 + lq) * 32 + hi * 8);
  const bf16x8 qb1 = *(const bf16x8*)(Qh + (size_t)(q0 + lq) * 32 + 16 + hi * 8);

  const u16* kg = Kh + wid * 512 + lane * 8;
  const u16* vg = Vh + wid * 512 + lane * 8;
  const int lds_w = wid * 1024;

#define STAGEA(CUR, I)                                                         \
  if (wid < 4) {                                                               \
    char* b_ = LDSB + (CUR) * 16384 + lds_w;                                   \
    GLDS16(kg + (size_t)(I) * 2048, b_);                                       \
    GLDS16(vg + (size_t)(I) * 2048, b_ + 4096);                                \
    GLDS16(kg + (size_t)(16 + (I)) * 2048, b_ + 8192);                         \
    GLDS16(vg + (size_t)(16 + (I)) * 2048, b_ + 12288);                        \
  }

  f32x16 acc = {};
  float la = 0.f, lb = 0.f, lc = 0.f, ld = 0.f;

  STAGEA(0, 0);
  __syncthreads();
  int cur = 0;
#pragma unroll 1
  for (int i = 0; i < 16; ++i) {
    if (i < 15) STAGEA(cur ^ 1, i + 1);
    const char* kb = LDSB + cur * 16384 + kh * 8192 + lane * 16;
    const bf16x8 ka0 = *(const bf16x8*)(kb);
    const bf16x8 ka1 = *(const bf16x8*)(kb + 1024);
    const bf16x8 ka2 = *(const bf16x8*)(kb + 2048);
    const bf16x8 ka3 = *(const bf16x8*)(kb + 3072);
    const bf16x8 va0 = *(const bf16x8*)(kb + 4096);
    const bf16x8 va1 = *(const bf16x8*)(kb + 5120);
    const bf16x8 va2 = *(const bf16x8*)(kb + 6144);
    const bf16x8 va3 = *(const bf16x8*)(kb + 7168);
    attn_tile(ka0, ka1, ka2, ka3, va0, va1, va2, va3, qb0, qb1,
              acc, la, lb, lc, ld);
    __syncthreads();
    cur ^= 1;
  }
#undef STAGEA

  float lrun = (la + lb) + (lc + ld);
  lrun += __shfl_xor(lrun, 32);

  float* sm_acc = (float*)LDSB;            // [4][64][16] = 16KB
  float* sm_l = (float*)(LDSB + 16384);    // [4][32]
  if (kh == 1) {
    sm_l[qg * 32 + lq] = lrun;
#pragma unroll
    for (int r = 0; r < 16; ++r) sm_acc[(qg * 64 + lane) * 16 + r] = acc[r];
  }
  __syncthreads();
  if (kh == 0) {
    const float inv = 1.f / (lrun + sm_l[qg * 32 + lq]);
    const int bb = bh >> 5, h = bh & 31;
    u16* o = O + (size_t)(bb * 2048 + q0 + lq) * 1024 + h * 32;
#pragma unroll
    for (int g = 0; g < 4; ++g) {
      ushort4 st;
      st.x = f2b((acc[g * 4 + 0] + sm_acc[(qg * 64 + lane) * 16 + g * 4 + 0]) * inv);
      st.y = f2b((acc[g * 4 + 1] + sm_acc[(qg * 64 + lane) * 16 + g * 4 + 1]) * inv);
      st.z = f2b((acc[g * 4 + 2] + sm_acc[(qg * 64 + lane) * 16 + g * 4 + 2]) * inv);
      st.w = f2b((acc[g * 4 + 3] + sm_acc[(qg * 64 + lane) * 16 + g * 4 + 3]) * inv);
      *(ushort4*)(o + g * 8 + hi * 4) = st;
    }
  }
}

// ---------------- LN1 merge: x = pw0+pw1 (bf16) + res(xb) + bo; LN -> r1b ---
__global__ __launch_bounds__(256) void ln1merge_kernel(
    const u16* __restrict__ P0, const u16* __restrict__ P1,
    const u16* __restrict__ R, const float* __restrict__ bias,
    const float* __restrict__ g, const float* __restrict__ b,
    u16* __restrict__ out) {
  const int wid = threadIdx.x >> 6, lane = threadIdx.x & 63;
  const int row = blockIdx.x * 4 + wid;
  const ushort4* A4 = (const ushort4*)(P0 + (size_t)row * 1024);
  const ushort4* B4 = (const ushort4*)(P1 + (size_t)row * 1024);
  const ushort4* R4 = (const ushort4*)(R + (size_t)row * 1024);
  const float4* Bi4 = (const float4*)bias;
  float4 xs[4];
  float s = 0.f, sq = 0.f;
#pragma unroll
  for (int i = 0; i < 4; ++i) {
    const int c = lane + i * 64;
    const ushort4 a = A4[c], pb = B4[c], rr = R4[c];
    const float4 bi = Bi4[c];
    float4 x;
    x.x = (b2f(a.x) + b2f(pb.x)) + b2f(rr.x) + bi.x;
    x.y = (b2f(a.y) + b2f(pb.y)) + b2f(rr.y) + bi.y;
    x.z = (b2f(a.z) + b2f(pb.z)) + b2f(rr.z) + bi.z;
    x.w = (b2f(a.w) + b2f(pb.w)) + b2f(rr.w) + bi.w;
    xs[i] = x;
    s += x.x + x.y + x.z + x.w;
    sq += x.x * x.x + x.y * x.y + x.z * x.z + x.w * x.w;
  }
#pragma unroll
  for (int m = 1; m < 64; m <<= 1) { s += __shfl_xor(s, m); sq += __shfl_xor(sq, m); }
  const float mean = s * (1.f / 1024.f);
  float var = sq * (1.f / 1024.f) - mean * mean;
  var = var > 0.f ? var : 0.f;
  const float rstd = rsqrtf(var + 1e-5f);
  const float4* g4 = (const float4*)g;
  const float4* b4 = (const float4*)b;
  ushort4* of = (ushort4*)(out + (size_t)row * 1024);
#pragma unroll
  for (int i = 0; i < 4; ++i) {
    const int c = lane + i * 64;
    const float4 gv = g4[c], bv = b4[c], x = xs[i];
    ushort4 yb;
    yb.x = f2b((x.x - mean) * rstd * gv.x + bv.x);
    yb.y = f2b((x.y - mean) * rstd * gv.y + bv.y);
    yb.z = f2b((x.z - mean) * rstd * gv.z + bv.z);
    yb.w = f2b((x.w - mean) * rstd * gv.w + bv.w);
    of[c] = yb;
  }
}

// ---------------- LN2: x = p0+p1+p2+p3 (bf16) + res(bf16) + bias ------------
__global__ __launch_bounds__(256) void ln2sum_kernel(
    const u16* __restrict__ P0, const u16* __restrict__ P1,
    const u16* __restrict__ P2, const u16* __restrict__ P3,
    const u16* __restrict__ R, const float* __restrict__ bias,
    const float* __restrict__ g, const float* __restrict__ b,
    float* __restrict__ out) {
  const int wid = threadIdx.x >> 6, lane = threadIdx.x & 63;
  const int row = blockIdx.x * 4 + wid;
  const ushort4* A4 = (const ushort4*)(P0 + (size_t)row * 1024);
  const ushort4* B4 = (const ushort4*)(P1 + (size_t)row * 1024);
  const ushort4* C4 = (const ushort4*)(P2 + (size_t)row * 1024);
  const ushort4* D4 = (const ushort4*)(P3 + (size_t)row * 1024);
  const ushort4* R4 = (const ushort4*)(R + (size_t)row * 1024);
  const float4* Bi4 = (const float4*)bias;
  float4 xs[4];
  float s = 0.f, sq = 0.f;
#pragma unroll
  for (int i = 0; i < 4; ++i) {
    const int c = lane + i * 64;
    const ushort4 a = A4[c], pb = B4[c], pc = C4[c], pd = D4[c], rr = R4[c];
    const float4 bi = Bi4[c];
    float4 x;
    x.x = (b2f(a.x) + b2f(pb.x)) + (b2f(pc.x) + b2f(pd.x)) + b2f(rr.x) + bi.x;
    x.y = (b2f(a.y) + b2f(pb.y)) + (b2f(pc.y) + b2f(pd.y)) + b2f(rr.y) + bi.y;
    x.z = (b2f(a.z) + b2f(pb.z)) + (b2f(pc.z) + b2f(pd.z)) + b2f(rr.z) + bi.z;
    x.w = (b2f(a.w) + b2f(pb.w)) + (b2f(pc.w) + b2f(pd.w)) + b2f(rr.w) + bi.w;
    xs[i] = x;
    s += x.x + x.y + x.z + x.w;
    sq += x.x * x.x + x.y * x.y + x.z * x.z + x.w * x.w;
  }
#pragma unroll
  for (int m = 1; m < 64; m <<= 1) { s += __shfl_xor(s, m); sq += __shfl_xor(sq, m); }
  const float mean = s * (1.f / 1024.f);
  float var = sq * (1.f / 1024.f) - mean * mean;
  var = var > 0.f ? var : 0.f;
  const float rstd = rsqrtf(var + 1e-5f);
  const float4* g4 = (const float4*)g;
  const float4* b4 = (const float4*)b;
  float4* of = (float4*)(out + (size_t)row * 1024);
#pragma unroll
  for (int i = 0; i < 4; ++i) {
    const int c = lane + i * 64;
    const float4 gv = g4[c], bv = b4[c], x = xs[i];
    float4 y;
    y.x = (x.x - mean) * rstd * gv.x + bv.x;
    y.y = (x.y - mean) * rstd * gv.y + bv.y;
    y.z = (x.z - mean) * rstd * gv.z + bv.z;
    y.w = (x.w - mean) * rstd * gv.w + bv.w;
    of[c] = y;
  }
}

// ---------------------------------------------------------------------------
extern "C" void kernel_launch(void* const* d_in, const int* in_sizes, int n_in,
                              void* d_out, int out_size, void* d_ws,
                              size_t ws_size, hipStream_t stream) {
  const float* x   = (const float*)d_in[0];
  const float* Wq  = (const float*)d_in[1];
  const float* bq  = (const float*)d_in[2];
  const float* Wk  = (const float*)d_in[3];
  const float* bk  = (const float*)d_in[4];
  const float* Wv  = (const float*)d_in[5];
  const float* bv  = (const float*)d_in[6];
  const float* kW  = (const float*)d_in[7];
  const float* Wo  = (const float*)d_in[8];
  const float* bo  = (const float*)d_in[9];
  const float* W1  = (const float*)d_in[10];
  const float* b1  = (const float*)d_in[11];
  const float* W2  = (const float*)d_in[12];
  const float* b2  = (const float*)d_in[13];
  const float* g1  = (const float*)d_in[14];
  const float* be1 = (const float*)d_in[15];
  const float* g2  = (const float*)d_in[16];
  const float* be2 = (const float*)d_in[17];

  char* ws = (char*)d_ws;
  const size_t MB = 1024 * 1024;
  u16*   WqT = (u16*)(ws + 0 * MB);   // [0,6) = fused QKV BT[3072][1024]
  u16*   WoT = (u16*)(ws + 6 * MB);
  u16*   W1T = (u16*)(ws + 8 * MB);
  u16*   W2T = (u16*)(ws + 16 * MB);
  u16*   r1b = (u16*)(ws + 24 * MB);  // bf16 residual stream [24,32)
  u16*   xb  = (u16*)(ws + 40 * MB);
  u16*   qhB = (u16*)(ws + 48 * MB);
  u16*   khB = (u16*)(ws + 56 * MB);
  u16*   vTB = (u16*)(ws + 64 * MB);
  u16*   hf  = (u16*)(ws + 40 * MB);  // FFN1 out, aliases xb..vT (dead)
  u16*   ao  = (u16*)(ws + 72 * MB);
  u16*   pw0 = (u16*)(ws + 48 * MB);  // Wo partials (qh/kh dead after attn)
  u16*   pw1 = (u16*)(ws + 56 * MB);
  u16*   p0  = (u16*)(ws + 0 * MB);   // FFN2 bf16 partials (dead regions)
  u16*   p2  = (u16*)(ws + 72 * MB);

  const dim3 blk(256);

  prep_kernel<<<16384, blk, 0, stream>>>(Wq, Wk, Wv, Wo, W1, W2, x,
                                         WqT, WoT, W1T, W2T, xb);

  gemmT<5, 128><<<dim3(24, 32), blk, 0, stream>>>(
      xb, WqT, bq, bk, bv, nullptr, qhB, kW, 3072, 1024);

  attn_kernel<<<1024, dim3(512), 0, stream>>>(qhB, khB, vTB, ao);

  // Wo: BN=128 split-K 2-way, bf16 partials pw0/pw1 (512 blocks)
  gemmT<7, 128><<<dim3(8, 64), blk, 0, stream>>>(
      ao, WoT, nullptr, nullptr, nullptr, (const float*)pw1, pw0, nullptr,
      1024, 1024);
  // LN1 merge: pw0+pw1+bo+xb -> LN -> r1b
  ln1merge_kernel<<<1024, blk, 0, stream>>>(pw0, pw1, xb, bo, g1, be1, r1b);
  // FFN1
  gemmT<3, 128><<<dim3(32, 32), blk, 0, stream>>>(
      r1b, W1T, b1, nullptr, nullptr, nullptr, hf, nullptr, 4096, 1024);
  // FFN2: BN=128, split-K 4-way, bf16 partials p0..p3 (1024 blocks)
  gemmT<6, 128><<<dim3(8, 128), blk, 0, stream>>>(
      hf, W2T, nullptr, nullptr, nullptr, (const float*)p2, p0, nullptr,
      1024, 4096);
  ln2sum_kernel<<<1024, blk, 0, stream>>>(p0, p0 + 4194304, p2, p2 + 4194304,
                                          r1b, b2, g2, be2, (float*)d_out);

  (void)in_sizes; (void)n_in; (void)out_size; (void)ws_size;
}